// Round 1
// baseline (9960.382 us; speedup 1.0000x reference)
//
#include <hip/hip_runtime.h>

#define SEQ  4096
#define NB   64
#define NI   64
#define NH   256

typedef short  bf16x8 __attribute__((ext_vector_type(8)));
typedef short  bf16x4 __attribute__((ext_vector_type(4)));
typedef float  f32x4  __attribute__((ext_vector_type(4)));

__device__ __forceinline__ unsigned short f2bf(float f) {
    union { float f; unsigned u; } v; v.f = f;
    return (unsigned short)((v.u + 0x7fffu + ((v.u >> 16) & 1u)) >> 16);
}
__device__ __forceinline__ float bflo(int p) {
    union { int i; float f; } u; u.i = p << 16; return u.f;
}
__device__ __forceinline__ float bfhi(int p) {
    union { int i; float f; } u; u.i = p & 0xffff0000; return u.f;
}
__device__ __forceinline__ float fast_rcp(float x) { return __builtin_amdgcn_rcpf(x); }
__device__ __forceinline__ float sigm(float x) { return fast_rcp(1.f + __expf(-x)); }
__device__ __forceinline__ float tanh_(float x) {
    x = fminf(15.f, fmaxf(-15.f, x));
    float e = __expf(2.f * x);
    return (e - 1.f) * fast_rcp(e + 1.f);
}
__device__ __forceinline__ f32x4 mfma16(bf16x8 a, bf16x8 b, f32x4 c) {
    return __builtin_amdgcn_mfma_f32_16x16x32_bf16(a, b, c, 0, 0, 0);
}
__device__ __forceinline__ bf16x8 ldfrag(const float* p) {
    float4 a = *(const float4*)p;
    float4 b = *(const float4*)(p + 4);
    bf16x8 r;
    r[0] = (short)f2bf(a.x); r[1] = (short)f2bf(a.y);
    r[2] = (short)f2bf(a.z); r[3] = (short)f2bf(a.w);
    r[4] = (short)f2bf(b.x); r[5] = (short)f2bf(b.y);
    r[6] = (short)f2bf(b.z); r[7] = (short)f2bf(b.w);
    return r;
}

// ============ xg precompute: unchanged ======================================
__global__ __launch_bounds__(1024) void xg_pre(
        const float* __restrict__ x, const float* __restrict__ w_ih,
        const float* __restrict__ b_ih, const float* __restrict__ b_hh,
        short* __restrict__ xg, size_t plane, int t0, int ns)
{
    const int tid = threadIdx.x, wv = tid >> 6, lane = tid & 63;
    const int nn = lane & 15, q = lane >> 4;
    const int jb = wv;

    bf16x8 w[3][2];
    float bias[3];
    #pragma unroll
    for (int g = 0; g < 3; ++g) {
        const int row = g * NH + jb * 16 + nn;
        w[g][0] = ldfrag(w_ih + row * NI + q * 8);
        w[g][1] = ldfrag(w_ih + row * NI + 32 + q * 8);
        bias[g] = b_ih[row] + (g < 2 ? b_hh[row] : 0.f);
    }

    const int NT = ns * 4;
    for (int rt = blockIdx.x; rt < NT; rt += gridDim.x) {
        const float* xr = x + ((size_t)t0 * NB + (size_t)rt * 16 + nn) * NI + q * 8;
        bf16x8 a0 = ldfrag(xr);
        bf16x8 a1 = ldfrag(xr + 32);
        #pragma unroll
        for (int g = 0; g < 3; ++g) {
            f32x4 acc = {0.f, 0.f, 0.f, 0.f};
            acc = mfma16(a0, w[g][0], acc);
            acc = mfma16(a1, w[g][1], acc);
            bf16x4 v;
            #pragma unroll
            for (int m = 0; m < 4; ++m) v[m] = (short)f2bf(acc[m] + bias[g]);
            *(bf16x4*)(xg + (size_t)g * plane +
                       (((size_t)rt * 16 + jb) * 64 + lane) * 4) = v;
        }
    }
}

// ============ recurrent kernel ==============================================
// RESTRUCTURED: grid 4 x 512 threads (8 waves, 2 waves/SIMD -> 256-reg budget).
// Wave wv owns TWO hidden j-blocks (2wv, 2wv+1): one av read feeds 6 MFMA
// chains, halving the per-step h-panel LDS traffic (128KB -> 64KB/step).
// Weights: wr/wz (both jb) + wn (even jb) in registers (160 regs); only the
// odd-jb n-gate stays in LDS (64KB resident, 64KB/step reads vs 128KB before).
// xg gate values are prefetched one step ahead (6x dwordx2) so the streamed
// HBM read latency is off the critical path.
// LDS: wnlds 64K | abuf 16K | fcwl 8K | oring 4K = 92 KB.
__global__ __launch_bounds__(512, 2) void gru_rec(
        const short* __restrict__ xg, size_t plane,
        const float* __restrict__ w_hh,
        const float* __restrict__ b_hh,
        const float* __restrict__ fc_w,
        const float* __restrict__ fc_b,
        float* __restrict__ out,
        float* __restrict__ hcar,
        int t0, int ns)
{
    __shared__ __attribute__((aligned(16))) short wnlds[32768]; // odd-jb n W_hh
    __shared__ __attribute__((aligned(16))) short abuf[8192];   // h staging x2
    __shared__ __attribute__((aligned(16))) short fcwl[4096];   // fc B-frags
    __shared__ __attribute__((aligned(16))) float oring[1024];  // out ring

    const int tid = threadIdx.x, wv = tid >> 6, lane = tid & 63;
    const int nn = lane & 15, q = lane >> 4;
    const int bc = blockIdx.x, bbase = bc * 16;

    // ---- one-time staging ----
    bf16x8 wr[2][8], wz[2][8], wn0[8];
    #pragma unroll
    for (int p = 0; p < 2; ++p) {
        const int row = (wv * 2 + p) * 16 + nn;
        #pragma unroll
        for (int c = 0; c < 8; ++c) {
            wr[p][c] = ldfrag(w_hh + (0 * NH + row) * NH + c * 32 + q * 8);
            wz[p][c] = ldfrag(w_hh + (1 * NH + row) * NH + c * 32 + q * 8);
        }
    }
    #pragma unroll
    for (int c = 0; c < 8; ++c)
        wn0[c] = ldfrag(w_hh + (2 * NH + (wv * 2) * 16 + nn) * NH + c * 32 + q * 8);
    #pragma unroll
    for (int c = 0; c < 8; ++c) {
        bf16x8 f = ldfrag(w_hh + (2 * NH + (wv * 2 + 1) * 16 + nn) * NH + c * 32 + q * 8);
        *(bf16x8*)(wnlds + (wv * 8 + c) * 512 + lane * 8) = f;
    }
    {   // fc B-frag: col nn==0 = fc_w, else 0; wave wv stages chunk wv (8 waves)
        bf16x8 f = 0;
        if (nn == 0) f = ldfrag(fc_w + wv * 32 + q * 8);
        *(bf16x8*)(fcwl + wv * 512 + lane * 8) = f;
    }
    const float bhn0 = b_hh[2 * NH + (wv * 2) * 16 + nn];
    const float bhn1 = b_hh[2 * NH + (wv * 2 + 1) * 16 + nn];
    const float fcb  = fc_b[0];

    // ---- h init ----
    f32x4 hp0 = {0.f, 0.f, 0.f, 0.f}, hp1 = {0.f, 0.f, 0.f, 0.f};
    if (t0 == 0) {
        ((int4*)abuf)[tid]       = make_int4(0, 0, 0, 0);
        ((int4*)abuf)[tid + 512] = make_int4(0, 0, 0, 0);
    } else {
        #pragma unroll
        for (int m = 0; m < 4; ++m) {
            hp0[m] = hcar[(size_t)(bbase + q * 4 + m) * NH + (wv * 2) * 16 + nn];
            hp1[m] = hcar[(size_t)(bbase + q * 4 + m) * NH + (wv * 2 + 1) * 16 + nn];
        }
        #pragma unroll
        for (int i = 0; i < 2; ++i) {
            const int f = (tid + i * 512) * 4, b = f >> 8, k0 = f & 255;
            float4 v = *(const float4*)(hcar + (size_t)(bbase + b) * NH + k0);
            bf16x4 s; s[0] = (short)f2bf(v.x); s[1] = (short)f2bf(v.y);
            s[2] = (short)f2bf(v.z); s[3] = (short)f2bf(v.w);
            *(bf16x4*)(abuf + (k0 >> 5) * 512 + (((k0 >> 3) & 3) * 16 + b) * 8 + (k0 & 7)) = s;
        }
    }

    const int j0 = wv * 32 + nn, j1 = j0 + 16;
    const int koff0 = (j0 >> 5) * 512 + ((j0 >> 3) & 3) * 128 + (j0 & 7) + q * 32;
    const int koff1 = (j1 >> 5) * 512 + ((j1 >> 3) & 3) * 128 + (j1 & 7) + q * 32;
    const short* xgp = xg + (((size_t)bc * 16 + wv * 2) * 64 + lane) * 4;
    __syncthreads();

    // prefetch regs for step 0
    int2 pr0 = *(const int2*)(xgp);
    int2 pr1 = *(const int2*)(xgp + 256);
    int2 pz0 = *(const int2*)(xgp + plane);
    int2 pz1 = *(const int2*)(xgp + plane + 256);
    int2 pn0 = *(const int2*)(xgp + 2 * plane);
    int2 pn1 = *(const int2*)(xgp + 2 * plane + 256);

    for (int t = 0; t < ns; ++t) {
        const int cur = t & 1, nxt = cur ^ 1;

        // consume prefetched gate values; issue prefetch for t+1
        const int2 gr0 = pr0, gr1 = pr1, gz0 = pz0, gz1 = pz1;
        const int2 gn0 = pn0, gn1 = pn1;
        const short* xq = xgp + ((t + 1 < ns) ? 16384 : 0);
        pr0 = *(const int2*)(xq);
        pr1 = *(const int2*)(xq + 256);
        pz0 = *(const int2*)(xq + plane);
        pz1 = *(const int2*)(xq + plane + 256);
        pn0 = *(const int2*)(xq + 2 * plane);
        pn1 = *(const int2*)(xq + 2 * plane + 256);
        xgp = xq;

        // out flush, once per 32 steps (slots all >=1 barrier old)
        if ((t & 31) == 1 && t >= 33) {
            const int s0 = t - 33;
            out[((size_t)(t0 + s0 + (tid >> 4))) * NB + bbase + (tid & 15)] =
                oring[(((s0 >> 5) & 1) << 9) + (tid >> 4) * 16 + (tid & 15)];
        }

        const bool isfc = (t > 0) && (wv == (t & 7));
        f32x4 ar0 = {0.f,0.f,0.f,0.f}, az0 = {0.f,0.f,0.f,0.f}, an0 = {0.f,0.f,0.f,0.f};
        f32x4 ar1 = {0.f,0.f,0.f,0.f}, az1 = {0.f,0.f,0.f,0.f}, an1 = {0.f,0.f,0.f,0.f};
        f32x4 afc = {0.f,0.f,0.f,0.f};
        const short* ab = abuf + cur * 4096;
        #pragma unroll
        for (int c = 0; c < 8; ++c) {
            bf16x8 av = *(const bf16x8*)(ab + c * 512 + lane * 8);
            ar0 = mfma16(av, wr[0][c], ar0);
            az0 = mfma16(av, wz[0][c], az0);
            an0 = mfma16(av, wn0[c], an0);
            ar1 = mfma16(av, wr[1][c], ar1);
            az1 = mfma16(av, wz[1][c], az1);
            bf16x8 wnf = *(const bf16x8*)(wnlds + (wv * 8 + c) * 512 + lane * 8);
            an1 = mfma16(av, wnf, an1);
            if (isfc) {   // rotating wave: FC(h_{t-1}) rides on the same av
                bf16x8 ff = *(const bf16x8*)(fcwl + c * 512 + lane * 8);
                afc = mfma16(av, ff, afc);
            }
        }
        if (isfc && nn == 0) {
            const int s = t - 1;
            f32x4 v;
            #pragma unroll
            for (int m = 0; m < 4; ++m) v[m] = afc[m] + fcb;
            *(f32x4*)(oring + (((s >> 5) & 1) << 9) + ((s & 31) << 4) + q * 4) = v;
        }

        // nonlinearity, j-block 2wv
        {
            const float xr4[4] = { bflo(gr0.x), bfhi(gr0.x), bflo(gr0.y), bfhi(gr0.y) };
            const float xz4[4] = { bflo(gz0.x), bfhi(gz0.x), bflo(gz0.y), bfhi(gz0.y) };
            const float xn4[4] = { bflo(gn0.x), bfhi(gn0.x), bflo(gn0.y), bfhi(gn0.y) };
            short* hw = abuf + nxt * 4096 + koff0;
            #pragma unroll
            for (int m = 0; m < 4; ++m) {
                float r_ = sigm(ar0[m] + xr4[m]);
                float z_ = sigm(az0[m] + xz4[m]);
                float n_ = tanh_(fmaf(r_, an0[m] + bhn0, xn4[m]));
                float h_ = n_ + z_ * (hp0[m] - n_);
                hp0[m] = h_;
                hw[m * 8] = (short)f2bf(h_);
            }
        }
        // nonlinearity, j-block 2wv+1
        {
            const float xr4[4] = { bflo(gr1.x), bfhi(gr1.x), bflo(gr1.y), bfhi(gr1.y) };
            const float xz4[4] = { bflo(gz1.x), bfhi(gz1.x), bflo(gz1.y), bfhi(gz1.y) };
            const float xn4[4] = { bflo(gn1.x), bfhi(gn1.x), bflo(gn1.y), bfhi(gn1.y) };
            short* hw = abuf + nxt * 4096 + koff1;
            #pragma unroll
            for (int m = 0; m < 4; ++m) {
                float r_ = sigm(ar1[m] + xr4[m]);
                float z_ = sigm(az1[m] + xz4[m]);
                float n_ = tanh_(fmaf(r_, an1[m] + bhn1, xn4[m]));
                float h_ = n_ + z_ * (hp1[m] - n_);
                hp1[m] = h_;
                hw[m * 8] = (short)f2bf(h_);
            }
        }
        __syncthreads();   // single per-step barrier
    }

    // ---- tail: FC for step ns-1, flush last 32, h carry ----
    if (wv == 0) {
        const short* ab = abuf + (ns & 1) * 4096;
        f32x4 afc = {0.f, 0.f, 0.f, 0.f};
        #pragma unroll
        for (int c = 0; c < 8; ++c)
            afc = mfma16(*(const bf16x8*)(ab + c * 512 + lane * 8),
                         *(const bf16x8*)(fcwl + c * 512 + lane * 8), afc);
        if (nn == 0) {
            const int s = ns - 1;
            f32x4 v;
            #pragma unroll
            for (int m = 0; m < 4; ++m) v[m] = afc[m] + fcb;
            *(f32x4*)(oring + (((s >> 5) & 1) << 9) + ((s & 31) << 4) + q * 4) = v;
        }
    }
    __syncthreads();
    {
        const int s0 = ns - 32;
        out[((size_t)(t0 + s0 + (tid >> 4))) * NB + bbase + (tid & 15)] =
            oring[(((s0 >> 5) & 1) << 9) + (tid >> 4) * 16 + (tid & 15)];
    }
    #pragma unroll
    for (int m = 0; m < 4; ++m) {
        hcar[(size_t)(bbase + q * 4 + m) * NH + wv * 32 + nn]      = hp0[m];
        hcar[(size_t)(bbase + q * 4 + m) * NH + wv * 32 + 16 + nn] = hp1[m];
    }
}

extern "C" void kernel_launch(void* const* d_in, const int* in_sizes, int n_in,
                              void* d_out, int out_size, void* d_ws, size_t ws_size,
                              hipStream_t stream) {
    (void)in_sizes; (void)n_in; (void)out_size;
    const float* x    = (const float*)d_in[0];
    const float* w_ih = (const float*)d_in[1];
    const float* w_hh = (const float*)d_in[2];
    const float* b_ih = (const float*)d_in[3];
    const float* b_hh = (const float*)d_in[4];
    const float* fc_w = (const float*)d_in[5];
    const float* fc_b = (const float*)d_in[6];
    float* out  = (float*)d_out;
    float* hcar = (float*)d_ws;                       // 64 KB h carry
    short* xg   = (short*)((char*)d_ws + 65536);      // 3 gate planes

    const size_t per_step = (size_t)NB * 3 * NH * 2;  // 98304 B / step
    long avail = (long)ws_size - 65536;
    int spc = 64;
    if (avail >= (long)per_step * 64) {
        spc = (int)((avail / (long)per_step) / 64) * 64;
        if (spc > SEQ) spc = SEQ;
    }
    for (int t0 = 0; t0 < SEQ; t0 += spc) {
        int ns = (SEQ - t0 < spc) ? (SEQ - t0) : spc;
        size_t plane = (size_t)spc * 16384;           // shorts per gate plane
        xg_pre<<<dim3(2048), dim3(1024), 0, stream>>>(x, w_ih, b_ih, b_hh,
                                                      xg, plane, t0, ns);
        gru_rec<<<dim3(4), dim3(512), 0, stream>>>(xg, plane, w_hh, b_hh,
                                                   fc_w, fc_b, out, hcar,
                                                   t0, ns);
    }
}

// Round 2
// 8789.854 us; speedup vs baseline: 1.1332x; 1.1332x over previous
//
#include <hip/hip_runtime.h>

#define SEQ  4096
#define NB   64
#define NI   64
#define NH   256

typedef short  bf16x8 __attribute__((ext_vector_type(8)));
typedef short  bf16x4 __attribute__((ext_vector_type(4)));
typedef float  f32x4  __attribute__((ext_vector_type(4)));

__device__ __forceinline__ unsigned short f2bf(float f) {
    union { float f; unsigned u; } v; v.f = f;
    return (unsigned short)((v.u + 0x7fffu + ((v.u >> 16) & 1u)) >> 16);
}
__device__ __forceinline__ float bflo(int p) {
    union { int i; float f; } u; u.i = p << 16; return u.f;
}
__device__ __forceinline__ float bfhi(int p) {
    union { int i; float f; } u; u.i = p & 0xffff0000; return u.f;
}
__device__ __forceinline__ float fast_rcp(float x) { return __builtin_amdgcn_rcpf(x); }
__device__ __forceinline__ float sigm(float x) { return fast_rcp(1.f + __expf(-x)); }
// clamp-free tanh: 2/(1+e^{-2y}) - 1.  y->+inf: e->0 -> 1; y->-inf: e->inf -> rcp->0 -> -1.
__device__ __forceinline__ float tanh_(float y) {
    float e = __expf(-2.f * y);
    return fmaf(2.f, fast_rcp(1.f + e), -1.f);
}
__device__ __forceinline__ f32x4 mfma16(bf16x8 a, bf16x8 b, f32x4 c) {
    return __builtin_amdgcn_mfma_f32_16x16x32_bf16(a, b, c, 0, 0, 0);
}
__device__ __forceinline__ bf16x8 ldfrag(const float* p) {
    float4 a = *(const float4*)p;
    float4 b = *(const float4*)(p + 4);
    bf16x8 r;
    r[0] = (short)f2bf(a.x); r[1] = (short)f2bf(a.y);
    r[2] = (short)f2bf(a.z); r[3] = (short)f2bf(a.w);
    r[4] = (short)f2bf(b.x); r[5] = (short)f2bf(b.y);
    r[6] = (short)f2bf(b.z); r[7] = (short)f2bf(b.w);
    return r;
}

// ============ xg precompute: unchanged ======================================
__global__ __launch_bounds__(1024) void xg_pre(
        const float* __restrict__ x, const float* __restrict__ w_ih,
        const float* __restrict__ b_ih, const float* __restrict__ b_hh,
        short* __restrict__ xg, size_t plane, int t0, int ns)
{
    const int tid = threadIdx.x, wv = tid >> 6, lane = tid & 63;
    const int nn = lane & 15, q = lane >> 4;
    const int jb = wv;

    bf16x8 w[3][2];
    float bias[3];
    #pragma unroll
    for (int g = 0; g < 3; ++g) {
        const int row = g * NH + jb * 16 + nn;
        w[g][0] = ldfrag(w_ih + row * NI + q * 8);
        w[g][1] = ldfrag(w_ih + row * NI + 32 + q * 8);
        bias[g] = b_ih[row] + (g < 2 ? b_hh[row] : 0.f);
    }

    const int NT = ns * 4;
    for (int rt = blockIdx.x; rt < NT; rt += gridDim.x) {
        const float* xr = x + ((size_t)t0 * NB + (size_t)rt * 16 + nn) * NI + q * 8;
        bf16x8 a0 = ldfrag(xr);
        bf16x8 a1 = ldfrag(xr + 32);
        #pragma unroll
        for (int g = 0; g < 3; ++g) {
            f32x4 acc = {0.f, 0.f, 0.f, 0.f};
            acc = mfma16(a0, w[g][0], acc);
            acc = mfma16(a1, w[g][1], acc);
            bf16x4 v;
            #pragma unroll
            for (int m = 0; m < 4; ++m) v[m] = (short)f2bf(acc[m] + bias[g]);
            *(bf16x4*)(xg + (size_t)g * plane +
                       (((size_t)rt * 16 + jb) * 64 + lane) * 4) = v;
        }
    }
}

// ============ recurrent kernel ==============================================
// 16-wave structure (proven 4353us) + VALU cuts:
//  - x-gate values fold into MFMA C-init (ar=xr, az=xz, an=bhn): -3 adds/elem
//  - clamp-free tanh (2*rcp(1+exp(-2y))-1): -6 ops/elem, no NaN path
//  - 1-step xg prefetch (from round 1) hides L3/HBM latency of the xg stream
// grid 4 x 1024 threads (16 waves, 4 waves/SIMD for phase overlap across waves).
// LDS: wlds 128K | abuf 16K | fcwl 8K | oring 4K = 156 KB.
__global__ __launch_bounds__(1024, 4) void gru_rec(
        const short* __restrict__ xg, size_t plane,
        const float* __restrict__ w_hh,
        const float* __restrict__ b_hh,
        const float* __restrict__ fc_w,
        const float* __restrict__ fc_b,
        float* __restrict__ out,
        float* __restrict__ hcar,
        int t0, int ns)
{
    __shared__ short wlds[65536];    // n-gate W_hh: 16 jb x 8 chunks x 512
    __shared__ short abuf[8192];     // h staging, 2 x 8 chunks x 512
    __shared__ short fcwl[4096];     // fc_w B-frags (col 0 only), 8 x 512
    __shared__ float oring[1024];    // out ring, 2 x 32 steps x 16 batch

    const int tid = threadIdx.x, wv = tid >> 6, lane = tid & 63;
    const int nn = lane & 15, q = lane >> 4;
    const int bc = blockIdx.x, bbase = bc * 16;

    // ---- one-time staging ----
    bf16x8 wr[8], wz[8];
    #pragma unroll
    for (int c = 0; c < 8; ++c)
        wr[c] = ldfrag(w_hh + (0 * NH + wv * 16 + nn) * NH + c * 32 + q * 8);
    #pragma unroll
    for (int c = 0; c < 8; ++c)
        wz[c] = ldfrag(w_hh + (1 * NH + wv * 16 + nn) * NH + c * 32 + q * 8);
    #pragma unroll
    for (int c = 0; c < 8; ++c) {
        bf16x8 f = ldfrag(w_hh + (2 * NH + wv * 16 + nn) * NH + c * 32 + q * 8);
        *(bf16x8*)(wlds + (wv * 8 + c) * 512 + lane * 8) = f;
    }
    if (wv < 8) {                    // fc B-frag: col nn==0 = fc_w, else 0
        bf16x8 f = 0;
        if (nn == 0) f = ldfrag(fc_w + wv * 32 + q * 8);
        *(bf16x8*)(fcwl + wv * 512 + lane * 8) = f;
    }
    const float bhn = b_hh[2 * NH + wv * 16 + nn];
    const float fcb = fc_b[0];

    // ---- h init ----
    f32x4 hp = {0.f, 0.f, 0.f, 0.f};
    if (t0 == 0) {
        ((int4*)abuf)[tid] = make_int4(0, 0, 0, 0);
    } else {
        #pragma unroll
        for (int m = 0; m < 4; ++m)
            hp[m] = hcar[(size_t)(bbase + q * 4 + m) * NH + wv * 16 + nn];
        const int f = tid * 4, b = f >> 8, k0 = f & 255;
        float4 v = *(const float4*)(hcar + (size_t)(bbase + b) * NH + k0);
        bf16x4 s; s[0] = (short)f2bf(v.x); s[1] = (short)f2bf(v.y);
        s[2] = (short)f2bf(v.z); s[3] = (short)f2bf(v.w);
        *(bf16x4*)(abuf + (k0 >> 5) * 512 + (((k0 >> 3) & 3) * 16 + b) * 8 + (k0 & 7)) = s;
    }

    const int j = wv * 16 + nn;
    const int koff = (j >> 5) * 512 + ((j >> 3) & 3) * 128 + (j & 7) + q * 32;
    const short* xgp = xg + ((size_t)(bc * 16 + wv) * 64 + lane) * 4;
    __syncthreads();

    // prefetch step-0 gate values
    int2 pr = *(const int2*)(xgp);
    int2 pz = *(const int2*)(xgp + plane);
    int2 pn = *(const int2*)(xgp + 2 * plane);

    for (int t = 0; t < ns; ++t) {
        const int cur = t & 1, nxt = cur ^ 1;

        // consume prefetched gate values; issue prefetch for t+1
        const int2 gx = pr, gz = pz, gn = pn;
        const short* xq = xgp + ((t + 1 < ns) ? 16384 : 0);
        pr = *(const int2*)(xq);
        pz = *(const int2*)(xq + plane);
        pn = *(const int2*)(xq + 2 * plane);
        xgp = xq;

        // out flush, once per 32 steps (slots all >=1 barrier old)
        if ((t & 31) == 1 && t >= 33 && tid < 512) {
            const int s0 = t - 33;
            out[((size_t)(t0 + s0 + (tid >> 4))) * NB + bbase + (tid & 15)] =
                oring[(((s0 >> 5) & 1) << 9) + (tid >> 4) * 16 + (tid & 15)];
        }

        const bool isfc = (t > 0) && (wv == (t & 15));
        // MFMA C-init carries the x-side gate values (b_hh for r,z folded
        // upstream in xg_pre; bhn folded here for n)
        f32x4 ar = { bflo(gx.x), bfhi(gx.x), bflo(gx.y), bfhi(gx.y) };
        f32x4 az = { bflo(gz.x), bfhi(gz.x), bflo(gz.y), bfhi(gz.y) };
        f32x4 an = { bhn, bhn, bhn, bhn };
        const float xn4[4] = { bflo(gn.x), bfhi(gn.x), bflo(gn.y), bfhi(gn.y) };
        f32x4 afc = {0.f,0.f,0.f,0.f};
        const short* ab = abuf + cur * 4096;
        #pragma unroll
        for (int c = 0; c < 8; ++c) {
            bf16x8 av = *(const bf16x8*)(ab + c * 512 + lane * 8);
            ar = mfma16(av, wr[c], ar);
            az = mfma16(av, wz[c], az);
            bf16x8 wnf = *(const bf16x8*)(wlds + (wv * 8 + c) * 512 + lane * 8);
            an = mfma16(av, wnf, an);
            if (isfc) {   // rotating wave: FC(h_{t-1}) rides on the same av
                bf16x8 ff = *(const bf16x8*)(fcwl + c * 512 + lane * 8);
                afc = mfma16(av, ff, afc);
            }
        }
        if (isfc && nn == 0) {
            const int s = t - 1;
            f32x4 v;
            #pragma unroll
            for (int m = 0; m < 4; ++m) v[m] = afc[m] + fcb;
            *(f32x4*)(oring + (((s >> 5) & 1) << 9) + ((s & 31) << 4) + q * 4) = v;
        }

        short* hw = abuf + nxt * 4096 + koff;
        #pragma unroll
        for (int m = 0; m < 4; ++m) {
            float r_ = sigm(ar[m]);                   // x-gate already in acc
            float z_ = sigm(az[m]);
            float y_ = fmaf(r_, an[m], xn4[m]);       // an = bhn + sum(h*wn)
            float n_ = tanh_(y_);
            float h_ = fmaf(z_, hp[m] - n_, n_);
            hp[m] = h_;
            hw[m * 8] = (short)f2bf(h_);
        }
        __syncthreads();   // single per-step barrier
    }

    // ---- tail: FC for step ns-1, flush last 32, h carry ----
    if (wv == 0) {
        const short* ab = abuf + (ns & 1) * 4096;
        f32x4 afc = {0.f, 0.f, 0.f, 0.f};
        #pragma unroll
        for (int c = 0; c < 8; ++c)
            afc = mfma16(*(const bf16x8*)(ab + c * 512 + lane * 8),
                         *(const bf16x8*)(fcwl + c * 512 + lane * 8), afc);
        if (nn == 0) {
            const int s = ns - 1;
            f32x4 v;
            #pragma unroll
            for (int m = 0; m < 4; ++m) v[m] = afc[m] + fcb;
            *(f32x4*)(oring + (((s >> 5) & 1) << 9) + ((s & 31) << 4) + q * 4) = v;
        }
    }
    __syncthreads();
    if (tid < 512) {
        const int s0 = ns - 32;
        out[((size_t)(t0 + s0 + (tid >> 4))) * NB + bbase + (tid & 15)] =
            oring[(((s0 >> 5) & 1) << 9) + (tid >> 4) * 16 + (tid & 15)];
    }
    #pragma unroll
    for (int m = 0; m < 4; ++m)
        hcar[(size_t)(bbase + q * 4 + m) * NH + wv * 16 + nn] = hp[m];
}

extern "C" void kernel_launch(void* const* d_in, const int* in_sizes, int n_in,
                              void* d_out, int out_size, void* d_ws, size_t ws_size,
                              hipStream_t stream) {
    (void)in_sizes; (void)n_in; (void)out_size;
    const float* x    = (const float*)d_in[0];
    const float* w_ih = (const float*)d_in[1];
    const float* w_hh = (const float*)d_in[2];
    const float* b_ih = (const float*)d_in[3];
    const float* b_hh = (const float*)d_in[4];
    const float* fc_w = (const float*)d_in[5];
    const float* fc_b = (const float*)d_in[6];
    float* out  = (float*)d_out;
    float* hcar = (float*)d_ws;                       // 64 KB h carry
    short* xg   = (short*)((char*)d_ws + 65536);      // 3 gate planes

    const size_t per_step = (size_t)NB * 3 * NH * 2;  // 98304 B / step
    long avail = (long)ws_size - 65536;
    int spc = 64;
    if (avail >= (long)per_step * 64) {
        spc = (int)((avail / (long)per_step) / 64) * 64;
        if (spc > SEQ) spc = SEQ;
    }
    for (int t0 = 0; t0 < SEQ; t0 += spc) {
        int ns = (SEQ - t0 < spc) ? (SEQ - t0) : spc;
        size_t plane = (size_t)spc * 16384;           // shorts per gate plane
        xg_pre<<<dim3(2048), dim3(1024), 0, stream>>>(x, w_ih, b_ih, b_hh,
                                                      xg, plane, t0, ns);
        gru_rec<<<dim3(4), dim3(1024), 0, stream>>>(xg, plane, w_hh, b_hh,
                                                    fc_w, fc_b, out, hcar,
                                                    t0, ns);
    }
}